// Round 20
// baseline (425.073 us; speedup 1.0000x reference)
//
#include <hip/hip_runtime.h>

// ResidualAttentionBlock on MI355X (gfx950).
// D=768 H=12 HD=64 NQ=100 KV=257 SEQ=357 BS=32.
// Round 20: attn-only tweaks on the R19 base (420.3us best):
//  (1) T5 s_setprio(1) around QK and PV MFMA clusters (m191 regime: independent waves,
//      no main-loop barriers -> +4-7% measured on attn),
//  (2) tree-reduce the softmax denominator (was a 17-deep serial add chain).
// Everything else byte-identical to R19.

typedef short bf16x8 __attribute__((ext_vector_type(8)));
typedef float f32x4 __attribute__((ext_vector_type(4)));
typedef unsigned short u16;
typedef unsigned long long u64;

__device__ __forceinline__ u16 f2b(float f) {
    unsigned u = __builtin_bit_cast(unsigned, f);
    u = (u + 0x7fffu + ((u >> 16) & 1u)) >> 16;  // RNE
    return (u16)u;
}
__device__ __forceinline__ float b2f(u16 h) {
    unsigned u = ((unsigned)h) << 16;
    return __builtin_bit_cast(float, u);
}
__device__ __forceinline__ unsigned pack2(float a, float b) {
    return (unsigned)f2b(a) | ((unsigned)f2b(b) << 16);
}
// async global->LDS, 16B per lane; LDS dest = wave-uniform base + lane*16
__device__ __forceinline__ void g2l16(const void* g, void* l) {
    __builtin_amdgcn_global_load_lds(
        (__attribute__((address_space(1))) void*)g,
        (__attribute__((address_space(3))) void*)l, 16, 0, 0);
}
#define MFMA16(a, b, c) __builtin_amdgcn_mfma_f32_16x16x32_bf16((a), (b), (c), 0, 0, 0)
#define SP1() __builtin_amdgcn_s_setprio(1)
#define SP0() __builtin_amdgcn_s_setprio(0)

// ---------------- LN row helper (one wave per row of 768) ----------------
__device__ __forceinline__ void ln_row(
    const float* __restrict__ in, const float* __restrict__ g, const float* __restrict__ be,
    u16* __restrict__ out, int row, int lane)
{
    const float* p = in + (size_t)row * 768;
    float4 a0 = *(const float4*)(p + lane * 4);
    float4 a1 = *(const float4*)(p + 256 + lane * 4);
    float4 a2 = *(const float4*)(p + 512 + lane * 4);
    float s = a0.x + a0.y + a0.z + a0.w + a1.x + a1.y + a1.z + a1.w + a2.x + a2.y + a2.z + a2.w;
    for (int o = 32; o; o >>= 1) s += __shfl_xor(s, o);
    float mean = s * (1.f / 768.f);
    float vs = 0.f;
#define SQA(t) { float dx; dx = t.x-mean; vs += dx*dx; dx = t.y-mean; vs += dx*dx; dx = t.z-mean; vs += dx*dx; dx = t.w-mean; vs += dx*dx; }
    SQA(a0) SQA(a1) SQA(a2)
#undef SQA
    for (int o = 32; o; o >>= 1) vs += __shfl_xor(vs, o);
    float rstd = rsqrtf(vs * (1.f / 768.f) + 1e-5f);
    u16* orow = out + (size_t)row * 768;
#pragma unroll
    for (int i = 0; i < 3; ++i) {
        int d = i * 256 + lane * 4;
        float4 av = (i == 0) ? a0 : ((i == 1) ? a1 : a2);
        float4 gv = *(const float4*)(g + d);
        float4 bv = *(const float4*)(be + d);
        ushort4 ov;
        ov.x = f2b((av.x - mean) * rstd * gv.x + bv.x);
        ov.y = f2b((av.y - mean) * rstd * gv.y + bv.y);
        ov.z = f2b((av.z - mean) * rstd * gv.z + bv.z);
        ov.w = f2b((av.w - mean) * rstd * gv.w + bv.w);
        *(ushort4*)(orow + d) = ov;
    }
}

// ---------------- fused: LN1 + mask bitmask pack + all-weight f32->bf16 cvt ----------------
__global__ __launch_bounds__(256) void prep_ln(
    const float* __restrict__ y, const float* __restrict__ l1g, const float* __restrict__ l1b,
    u16* __restrict__ xb,
    const int* __restrict__ m, u64* __restrict__ mo,
    const float* __restrict__ s0, const float* __restrict__ s1, const float* __restrict__ s2,
    const float* __restrict__ s3, const float* __restrict__ s4, u16* __restrict__ dst)
{
    const int bid = blockIdx.x;
    const int lane = threadIdx.x & 63;
    if (bid < 2856) {
        int row = bid * 4 + (threadIdx.x >> 6);
        if (row < 11424) ln_row(y, l1g, l1b, xb, row, lane);
        return;
    }
    const int cb = bid - 2856;
    if (cb < 800) {
        int row = cb * 4 + (threadIdx.x >> 6);
        if (row < 3200) {
            const int* r = m + (size_t)row * 257;
            u64 w0 = __ballot(r[lane] != 0);
            u64 w1 = __ballot(r[64 + lane] != 0);
            u64 w2 = __ballot(r[128 + lane] != 0);
            u64 w3 = __ballot(r[192 + lane] != 0);
            u64 w4 = __ballot(lane == 0 && r[256] != 0);
            if (lane == 0) {
                u64* p = mo + (size_t)row * 5;
                p[0] = w0; p[1] = w1; p[2] = w2; p[3] = w3; p[4] = w4;
            }
        }
    }
    int i = cb * 256 + threadIdx.x;
    const int stride = 2048 * 256;
    for (; i < 1916928; i += stride) {
        const float* src; int off;
        if (i < 442368)       { src = s0; off = i; }
        else if (i < 589824)  { src = s1; off = i - 442368; }
        else if (i < 737280)  { src = s2; off = i - 589824; }
        else if (i < 1327104) { src = s3; off = i - 737280; }
        else                  { src = s4; off = i - 1327104; }
        float4 v = ((const float4*)src)[off];
        ushort4 o;
        o.x = f2b(v.x); o.y = f2b(v.y); o.z = f2b(v.z); o.w = f2b(v.w);
        ((ushort4*)dst)[i] = o;
    }
}

// ---------------- LayerNorm standalone (LN2) ----------------
__global__ __launch_bounds__(256) void ln_kernel(
    const float* __restrict__ in, const float* __restrict__ g, const float* __restrict__ be,
    u16* __restrict__ out, int nrows)
{
    int row = blockIdx.x * 4 + (threadIdx.x >> 6);
    if (row < nrows) ln_row(in, g, be, out, row, threadIdx.x & 63);
}

// ---------------- GEMM body: BK=32, 2-buffer, column-group XCD traversal (R18/R19) ----------------
template<int ACT, int OUTBF, int RES>
__device__ __forceinline__ void gemm_body(
    u16 (*Al)[4096], u16 (*Bl)[4096],
    const u16* __restrict__ A, const u16* __restrict__ B,
    const float* __restrict__ bias, const float* __restrict__ res,
    void* __restrict__ Cp, int M, int N, int K, int G, int gx, int gy, int raw)
{
    const int t = threadIdx.x;
    const int lane = t & 63, w = t >> 6;
    const int wr = w >> 1, wc = w & 1;
    const int fr = lane & 15, fg = lane >> 4;

    const int rows_per = gx >> 3;                 // gx % 8 == 0
    const int xcd = raw & 7, idx = raw >> 3;
    const int bpg = rows_per * G;
    const int grp = idx / bpg, rem = idx - grp * bpg;
    const int nt = grp * G + rem % G;
    const int mt = xcd * rows_per + rem / G;
    const int m0 = mt * 128, n0 = nt * 128;
    if (m0 >= M) return;                          // padded tail block (uniform exit, pre-barrier)

    const int srow = lane >> 2;
    const int scol = (lane & 3) * 8;
    int ar0 = m0 + w * 32 + srow;      int ar1 = ar0 + 16;
    ar0 = ar0 < M ? ar0 : M - 1;       ar1 = ar1 < M ? ar1 : M - 1;
    int br0 = n0 + w * 32 + srow;      int br1 = br0 + 16;
    br0 = br0 < N ? br0 : N - 1;       br1 = br1 < N ? br1 : N - 1;
    const u16* a0p = A + (size_t)ar0 * K + scol;
    const u16* a1p = A + (size_t)ar1 * K + scol;
    const u16* b0p = B + (size_t)br0 * K + scol;
    const u16* b1p = B + (size_t)br1 * K + scol;
    const int lo0 = (w * 2 + 0) * 512, lo1 = (w * 2 + 1) * 512;

    const int nk = K >> 5;
    g2l16(a0p, &Al[0][lo0]);
    g2l16(a1p, &Al[0][lo1]);
    g2l16(b0p, &Bl[0][lo0]);
    g2l16(b1p, &Bl[0][lo1]);
    __syncthreads();

    f32x4 acc[4][4] = {};
#pragma unroll 2
    for (int ki = 0; ki < nk; ++ki) {
        const int cur = ki & 1;
        if (ki + 1 < nk) {               // issue next-tile loads BEFORE compute
            const int k0 = (ki + 1) << 5;
            const int nxt = cur ^ 1;
            g2l16(a0p + k0, &Al[nxt][lo0]);
            g2l16(a1p + k0, &Al[nxt][lo1]);
            g2l16(b0p + k0, &Bl[nxt][lo0]);
            g2l16(b1p + k0, &Bl[nxt][lo1]);
        }
        bf16x8 af[4], bfr[4];
#pragma unroll
        for (int m = 0; m < 4; ++m) af[m] = *(const bf16x8*)&Al[cur][(wr * 64 + m * 16 + fr) * 32 + fg * 8];
#pragma unroll
        for (int n = 0; n < 4; ++n) bfr[n] = *(const bf16x8*)&Bl[cur][(wc * 64 + n * 16 + fr) * 32 + fg * 8];
#pragma unroll
        for (int m = 0; m < 4; ++m)
#pragma unroll
            for (int n = 0; n < 4; ++n)
                acc[m][n] = MFMA16(af[m], bfr[n], acc[m][n]);
        __syncthreads();  // drains this wave's vmcnt(0) (next-tile loads) + barrier
    }
    // Epilogue. C/D layout: col = lane&15, row = (lane>>4)*4 + r  [measured m89/m91]
#pragma unroll
    for (int m = 0; m < 4; ++m) {
#pragma unroll
        for (int n = 0; n < 4; ++n) {
            int col = n0 + wc * 64 + n * 16 + fr;
            float bv = bias[col];
#pragma unroll
            for (int r = 0; r < 4; ++r) {
                int row = m0 + wr * 64 + m * 16 + fg * 4 + r;
                if (row < M) {
                    float v = acc[m][n][r] + bv;
                    if (RES) v += res[(size_t)row * N + col];
                    if (ACT) v = v / (1.f + __expf(-1.702f * v));  // QuickGELU
                    if (OUTBF) ((u16*)Cp)[(size_t)row * N + col] = f2b(v);
                    else       ((float*)Cp)[(size_t)row * N + col] = v;
                }
            }
        }
    }
}

template<int ACT, int OUTBF, int RES>
__global__ __launch_bounds__(256, 4) void gemm_bt(
    const u16* __restrict__ A, const u16* __restrict__ B,
    const float* __restrict__ bias, const float* __restrict__ res,
    void* __restrict__ Cp, int M, int N, int K, int G)
{
    __shared__ u16 Al[2][4096];
    __shared__ u16 Bl[2][4096];
    const int raw = blockIdx.x + gridDim.x * blockIdx.y;
    gemm_body<ACT, OUTBF, RES>(Al, Bl, A, B, bias, res, Cp, M, N, K, G,
                               gridDim.x, gridDim.y, raw);
}

// merged qkv + new_q
__global__ __launch_bounds__(256, 4) void gemm_qn(
    const u16* __restrict__ A0, const u16* __restrict__ B0, const float* __restrict__ b0,
    u16* __restrict__ C0,
    const u16* __restrict__ A1, const u16* __restrict__ B1, const float* __restrict__ b1,
    u16* __restrict__ C1)
{
    __shared__ u16 Al[2][4096];
    __shared__ u16 Bl[2][4096];
    const int raw = blockIdx.x;
    if (raw < 1296) {  // qkv: gx=72, gy=18, G=3
        gemm_body<0, 1, 0>(Al, Bl, A0, B0, b0, nullptr, C0, 8224, 2304, 768, 3, 72, 18, raw);
    } else {           // new_q: gx=32, gy=6, G=6
        gemm_body<0, 1, 0>(Al, Bl, A1, B1, b1, nullptr, C1, 3200, 768, 768, 6, 32, 6, raw - 1296);
    }
}

// ---------------- MFMA attention (R14 + T5 setprio + tree l-sum) ----------------
__global__ __launch_bounds__(256, 2) void attn_kernel(
    const u16* __restrict__ qkv,   // [257*32][2304] rows m*32+b; q|k|v at +0/+768/+1536
    const u16* __restrict__ nq,    // [100*32][768]  rows q*32+b
    const u64* __restrict__ mpk,   // [32*100][5] packed mask bits (1 = blocked)
    u16* __restrict__ out)         // [357*32][768]  rows q*32+b
{
    __shared__ u16 Kl[272 * 64];   // K rows, XOR-swizzled: byte ^= (row&7)<<4
    __shared__ u16 Vt[64 * 296];   // Vt[d][m], row stride 592B
    const int raw = blockIdx.x;
    const int bid = (raw & 7) * 48 + (raw >> 3);   // 384 = 8 XCDs x 48 contiguous
    const int b = bid / 12, h = bid % 12;
    const int t = threadIdx.x, lane = t & 63, wv = t >> 6;
    const int fr = lane & 15, fg = lane >> 4;

    for (int i = t; i < 2048; i += 256) {
        int d = i >> 5, c = 257 + (i & 31);
        if (c < 288) Vt[d * 296 + c] = 0;
    }
    {
        const int r8 = t >> 3, c8 = (t & 7) * 8;
        const u16* kb = qkv + 768 + h * 64 + c8;
        const u16* vb = qkv + 1536 + h * 64 + c8;
#pragma unroll 1
        for (int p = 0; p < 9; ++p) {
            int m = r8 + p * 32;
            if (m <= 256) {
                size_t go = (size_t)(m * 32 + b) * 2304;
                bf16x8 kv = *(const bf16x8*)(kb + go);
                int byte = m * 128 + c8 * 2;
                *(bf16x8*)((char*)Kl + (byte ^ ((m & 7) << 4))) = kv;
                bf16x8 vv = *(const bf16x8*)(vb + go);
#pragma unroll
                for (int j = 0; j < 8; ++j)
                    Vt[(c8 + j) * 296 + m] = (u16)vv[j];
            }
        }
    }
    __syncthreads();

    const int swzK = (fr & 7) << 4;
    const char* KlB = (const char*)Kl;
    const char* VtB = (const char*)Vt;
    const int psrc0 = fr + 32 * (fg & 1);          // shfl source lanes for PV redistribution
    const int psrc1 = psrc0 + 16;
    const bool phi = fg >= 2;

    auto fetch = [&](int ti, bf16x8& q0v, bf16x8& q1v, u64* mw, bool& im) {
        int q = ti * 16 + fr;
        int qc = q < 357 ? q : 356;
        im = qc < 100;
        const u16* qp = im ? (nq + (size_t)(qc * 32 + b) * 768 + h * 64)
                           : (qkv + (size_t)((qc - 100) * 32 + b) * 2304 + h * 64);
        q0v = *(const bf16x8*)(qp + fg * 8);
        q1v = *(const bf16x8*)(qp + 32 + fg * 8);
        if (im) {
            const u64* mp = mpk + (size_t)(b * 100 + qc) * 5;
            mw[0] = mp[0]; mw[1] = mp[1]; mw[2] = mp[2]; mw[3] = mp[3]; mw[4] = mp[4];
        } else {
            mw[0] = mw[1] = mw[2] = mw[3] = mw[4] = 0;
        }
    };

    bf16x8 qf0, qf1, qn0, qn1;
    u64 mwc[5], mwn[5];
    bool imc, imn;
    fetch(wv, qf0, qf1, mwc, imc);

#pragma unroll 1
    for (int ti = wv; ti < 23; ti += 4) {
        // ---- QK^T (transposed: acc col = q) ----
        f32x4 sc[17];
        SP1();
#pragma unroll
        for (int kt = 0; kt < 17; ++kt) {
            int rb = (kt * 16 + fr) * 128;
            bf16x8 ka0 = *(const bf16x8*)(KlB + ((rb + fg * 16) ^ swzK));
            bf16x8 ka1 = *(const bf16x8*)(KlB + ((rb + 64 + fg * 16) ^ swzK));
            f32x4 a = {0.f, 0.f, 0.f, 0.f};
            a = MFMA16(ka0, qf0, a);
            a = MFMA16(ka1, qf1, a);
            sc[kt] = a;
        }
        SP0();
        if (ti + 4 < 23) fetch(ti + 4, qn0, qn1, mwn, imn);
        // ---- mask + per-kt max4 (parallel) + tree reduce ----
        float tm[17];
#pragma unroll
        for (int kt = 0; kt < 17; ++kt) {
            u64 mw = (kt >> 2) == 0 ? mwc[0] : (kt >> 2) == 1 ? mwc[1] : (kt >> 2) == 2 ? mwc[2]
                   : (kt >> 2) == 3 ? mwc[3] : mwc[4];
            float s0, s1, s2, s3;
            {
                int key = kt * 16 + fg * 4;
                bool b0 = (key > 256) || (imc && ((mw >> (key & 63)) & 1ull));
                bool b1 = (key + 1 > 256) || (imc && ((mw >> ((key + 1) & 63)) & 1ull));
                bool b2 = (key + 2 > 256) || (imc && ((mw >> ((key + 2) & 63)) & 1ull));
                bool b3 = (key + 3 > 256) || (imc && ((mw >> ((key + 3) & 63)) & 1ull));
                s0 = b0 ? -INFINITY : sc[kt][0];
                s1 = b1 ? -INFINITY : sc[kt][1];
                s2 = b2 ? -INFINITY : sc[kt][2];
                s3 = b3 ? -INFINITY : sc[kt][3];
            }
            sc[kt][0] = s0; sc[kt][1] = s1; sc[kt][2] = s2; sc[kt][3] = s3;
            tm[kt] = fmaxf(fmaxf(s0, s1), fmaxf(s2, s3));
        }
        float m8_0 = fmaxf(tm[0], tm[8]),  m8_1 = fmaxf(tm[1], tm[9]);
        float m8_2 = fmaxf(tm[2], tm[10]), m8_3 = fmaxf(tm[3], tm[11]);
        float m8_4 = fmaxf(tm[4], tm[12]), m8_5 = fmaxf(tm[5], tm[13]);
        float m8_6 = fmaxf(tm[6], tm[14]), m8_7 = fmaxf(tm[7], tm[15]);
        float m4_0 = fmaxf(m8_0, m8_4), m4_1 = fmaxf(m8_1, m8_5);
        float m4_2 = fmaxf(m8_2, m8_6), m4_3 = fmaxf(m8_3, m8_7);
        float mx = fmaxf(fmaxf(fmaxf(m4_0, m4_1), fmaxf(m4_2, m4_3)), tm[16]);
        mx = fmaxf(mx, __shfl_xor(mx, 16));
        mx = fmaxf(mx, __shfl_xor(mx, 32));
        // ---- exp (scale folded), per-kt partial sums + tree, pack to bf16 pairs ----
        float ls[17];
        unsigned pk[17][2];
#pragma unroll
        for (int kt = 0; kt < 17; ++kt) {
            float p0 = __expf((sc[kt][0] - mx) * 0.125f);
            float p1 = __expf((sc[kt][1] - mx) * 0.125f);
            float p2 = __expf((sc[kt][2] - mx) * 0.125f);
            float p3 = __expf((sc[kt][3] - mx) * 0.125f);
            ls[kt] = (p0 + p1) + (p2 + p3);
            pk[kt][0] = pack2(p0, p1);
            pk[kt][1] = pack2(p2, p3);
        }
        float l8_0 = ls[0] + ls[8],  l8_1 = ls[1] + ls[9];
        float l8_2 = ls[2] + ls[10], l8_3 = ls[3] + ls[11];
        float l8_4 = ls[4] + ls[12], l8_5 = ls[5] + ls[13];
        float l8_6 = ls[6] + ls[14], l8_7 = ls[7] + ls[15];
        float l4_0 = l8_0 + l8_4, l4_1 = l8_1 + l8_5;
        float l4_2 = l8_2 + l8_6, l4_3 = l8_3 + l8_7;
        float l = ((l4_0 + l4_1) + (l4_2 + l4_3)) + ls[16];
        l += __shfl_xor(l, 16);
        l += __shfl_xor(l, 32);
        // ---- PV: O^T = V^T * P^T, P redistributed via shfl ----
        f32x4 oc[4] = {};
#pragma unroll
        for (int c = 0; c < 9; ++c) {
            unsigned p00 = pk[2 * c][0], p01 = pk[2 * c][1];
            unsigned p10 = (c < 8) ? pk[2 * c + 1][0] : 0u;
            unsigned p11 = (c < 8) ? pk[2 * c + 1][1] : 0u;
            unsigned a00 = __shfl(p00, psrc0), a01 = __shfl(p01, psrc0);
            unsigned a10 = __shfl(p10, psrc0), a11 = __shfl(p11, psrc0);
            unsigned b00 = __shfl(p00, psrc1), b01 = __shfl(p01, psrc1);
            unsigned b10 = __shfl(p10, psrc1), b11 = __shfl(p11, psrc1);
            uint4 pw;
            pw.x = phi ? a10 : a00;  pw.y = phi ? a11 : a01;
            pw.z = phi ? b10 : b00;  pw.w = phi ? b11 : b01;
            bf16x8 pf = __builtin_bit_cast(bf16x8, pw);
            SP1();
#pragma unroll
            for (int dt = 0; dt < 4; ++dt) {
                bf16x8 vf = *(const bf16x8*)(VtB + (dt * 16 + fr) * 592 + c * 64 + fg * 16);
                oc[dt] = MFMA16(vf, pf, oc[dt]);
            }
            SP0();
        }
        // ---- write O (lane q = fr, d = dt*16 + fg*4 + r) ----
        int q = ti * 16 + fr;
        if (q < 357) {
            float rl = 1.f / l;
            u16* op = out + (size_t)(q * 32 + b) * 768 + h * 64 + fg * 4;
#pragma unroll
            for (int dt = 0; dt < 4; ++dt) {
                ushort4 ov;
                ov.x = f2b(oc[dt][0] * rl); ov.y = f2b(oc[dt][1] * rl);
                ov.z = f2b(oc[dt][2] * rl); ov.w = f2b(oc[dt][3] * rl);
                *(ushort4*)(op + dt * 16) = ov;
            }
        }
        if (ti + 4 < 23) {
            qf0 = qn0; qf1 = qn1; imc = imn;
            mwc[0] = mwn[0]; mwc[1] = mwn[1]; mwc[2] = mwn[2]; mwc[3] = mwn[3]; mwc[4] = mwn[4];
        }
    }
}

// ---------------- launch ----------------
extern "C" void kernel_launch(void* const* d_in, const int* in_sizes, int n_in,
                              void* d_out, int out_size, void* d_ws, size_t ws_size,
                              hipStream_t stream)
{
    const float* y   = (const float*)d_in[0];
    const int*   msk = (const int*)  d_in[1];
    const float* ipw = (const float*)d_in[2];
    const float* ipb = (const float*)d_in[3];
    const float* nqw = (const float*)d_in[4];
    const float* nqb = (const float*)d_in[5];
    const float* ow  = (const float*)d_in[6];
    const float* ob  = (const float*)d_in[7];
    const float* l1g = (const float*)d_in[8];
    const float* l1b = (const float*)d_in[9];
    const float* l2g = (const float*)d_in[10];
    const float* l2b = (const float*)d_in[11];
    const float* fcw = (const float*)d_in[12];
    const float* fcb = (const float*)d_in[13];
    const float* pjw = (const float*)d_in[14];
    const float* pjb = (const float*)d_in[15];

    char* ws = (char*)d_ws;
    u16* x_b   = (u16*)(ws + 0);          // 11424 x 768
    u16* qkv_b = (u16*)(ws + 17547264);   //  8224 x 2304
    u16* nq_b  = (u16*)(ws + 55443456);   //  3200 x 768
    u16* ao_b  = (u16*)(ws + 60358656);   // 11424 x 768
    u16* h1_b  = (u16*)(ws + 0);          // 11424 x 3072 (phase 2, overlaps phase-1 region)
    u16* h_b   = (u16*)(ws + 77905920);   // 11424 x 768 (phase 2)
    u64* mpk_b = (u64*)(ws + 77905920);   // 3200 x 5 u64 (phase 1 only)
    u16* w_ip  = (u16*)(ws + 95453184);   // weights contiguous: ip|nq|out|fc|pj
    float* out = (float*)d_out;

    u16* w_nq  = w_ip + 1769472;
    u16* w_out = w_nq + 589824;
    u16* w_fc  = w_out + 589824;
    u16* w_pj  = w_fc + 2359296;

    // LN1 + mask-pack + weight-cvt fused
    prep_ln<<<4904, 256, 0, stream>>>(y, l1g, l1b, x_b, msk, mpk_b, ipw, nqw, ow, fcw, pjw, w_ip);
    // qkv + new_q fused (1296 + 192 blocks)
    gemm_qn<<<1488, 256, 0, stream>>>(x_b + (size_t)3200 * 768, w_ip, ipb, qkv_b,
                                      x_b, w_nq, nqb, nq_b);
    // attention
    attn_kernel<<<384, 256, 0, stream>>>(qkv_b, nq_b, mpk_b, ao_b);
    // y2 = y + attn_out @ out_w.T + out_b   (G=gy)
    gemm_bt<0, 0, 1><<<dim3(96, 6), 256, 0, stream>>>(ao_b, w_out, ob, y, out, 11424, 768, 768, 6);
    // h = LN2(y2) -> bf16
    ln_kernel<<<2856, 256, 0, stream>>>(out, l2g, l2b, h_b, 11424);
    // h1 = quickgelu(h @ fc_w.T + fc_b)   (G=4)
    gemm_bt<1, 1, 0><<<dim3(96, 24), 256, 0, stream>>>(h_b, w_fc, fcb, nullptr, h1_b, 11424, 3072, 768, 4);
    // out = y2 + h1 @ proj_w.T + proj_b   (G=3)
    gemm_bt<0, 0, 1><<<dim3(96, 6), 256, 0, stream>>>(h1_b, w_pj, pjb, out, out, 11424, 768, 3072, 3);
}

// Round 21
// 417.266 us; speedup vs baseline: 1.0187x; 1.0187x over previous
//
#include <hip/hip_runtime.h>

// ResidualAttentionBlock on MI355X (gfx950).
// D=768 H=12 HD=64 NQ=100 KV=257 SEQ=357 BS=32.
// Round 21 (FINAL): R19 configuration verbatim — best measured, 420.3us.
// R20's setprio + tree-l were neutral-negative and are reverted.
// Ladder: 1465 (R1) -> 526 (MFMA attn) -> 449 (XCD A-slice GEMM) -> 434.8 (attn chain
// cuts) -> 431.5 (column-group L2 residency) -> 420.3 (pipeline fusion).

typedef short bf16x8 __attribute__((ext_vector_type(8)));
typedef float f32x4 __attribute__((ext_vector_type(4)));
typedef unsigned short u16;
typedef unsigned long long u64;

__device__ __forceinline__ u16 f2b(float f) {
    unsigned u = __builtin_bit_cast(unsigned, f);
    u = (u + 0x7fffu + ((u >> 16) & 1u)) >> 16;  // RNE
    return (u16)u;
}
__device__ __forceinline__ float b2f(u16 h) {
    unsigned u = ((unsigned)h) << 16;
    return __builtin_bit_cast(float, u);
}
__device__ __forceinline__ unsigned pack2(float a, float b) {
    return (unsigned)f2b(a) | ((unsigned)f2b(b) << 16);
}
// async global->LDS, 16B per lane; LDS dest = wave-uniform base + lane*16
__device__ __forceinline__ void g2l16(const void* g, void* l) {
    __builtin_amdgcn_global_load_lds(
        (__attribute__((address_space(1))) void*)g,
        (__attribute__((address_space(3))) void*)l, 16, 0, 0);
}
#define MFMA16(a, b, c) __builtin_amdgcn_mfma_f32_16x16x32_bf16((a), (b), (c), 0, 0, 0)

// ---------------- LN row helper (one wave per row of 768) ----------------
__device__ __forceinline__ void ln_row(
    const float* __restrict__ in, const float* __restrict__ g, const float* __restrict__ be,
    u16* __restrict__ out, int row, int lane)
{
    const float* p = in + (size_t)row * 768;
    float4 a0 = *(const float4*)(p + lane * 4);
    float4 a1 = *(const float4*)(p + 256 + lane * 4);
    float4 a2 = *(const float4*)(p + 512 + lane * 4);
    float s = a0.x + a0.y + a0.z + a0.w + a1.x + a1.y + a1.z + a1.w + a2.x + a2.y + a2.z + a2.w;
    for (int o = 32; o; o >>= 1) s += __shfl_xor(s, o);
    float mean = s * (1.f / 768.f);
    float vs = 0.f;
#define SQA(t) { float dx; dx = t.x-mean; vs += dx*dx; dx = t.y-mean; vs += dx*dx; dx = t.z-mean; vs += dx*dx; dx = t.w-mean; vs += dx*dx; }
    SQA(a0) SQA(a1) SQA(a2)
#undef SQA
    for (int o = 32; o; o >>= 1) vs += __shfl_xor(vs, o);
    float rstd = rsqrtf(vs * (1.f / 768.f) + 1e-5f);
    u16* orow = out + (size_t)row * 768;
#pragma unroll
    for (int i = 0; i < 3; ++i) {
        int d = i * 256 + lane * 4;
        float4 av = (i == 0) ? a0 : ((i == 1) ? a1 : a2);
        float4 gv = *(const float4*)(g + d);
        float4 bv = *(const float4*)(be + d);
        ushort4 ov;
        ov.x = f2b((av.x - mean) * rstd * gv.x + bv.x);
        ov.y = f2b((av.y - mean) * rstd * gv.y + bv.y);
        ov.z = f2b((av.z - mean) * rstd * gv.z + bv.z);
        ov.w = f2b((av.w - mean) * rstd * gv.w + bv.w);
        *(ushort4*)(orow + d) = ov;
    }
}

// ---------------- fused: LN1 + mask bitmask pack + all-weight f32->bf16 cvt ----------------
// blocks [0,2856): LN1 (4 rows each). blocks [2856,4904): mask-pack head + cvt grid-stride.
__global__ __launch_bounds__(256) void prep_ln(
    const float* __restrict__ y, const float* __restrict__ l1g, const float* __restrict__ l1b,
    u16* __restrict__ xb,
    const int* __restrict__ m, u64* __restrict__ mo,
    const float* __restrict__ s0, const float* __restrict__ s1, const float* __restrict__ s2,
    const float* __restrict__ s3, const float* __restrict__ s4, u16* __restrict__ dst)
{
    const int bid = blockIdx.x;
    const int lane = threadIdx.x & 63;
    if (bid < 2856) {
        int row = bid * 4 + (threadIdx.x >> 6);
        if (row < 11424) ln_row(y, l1g, l1b, xb, row, lane);
        return;
    }
    const int cb = bid - 2856;
    if (cb < 800) {
        int row = cb * 4 + (threadIdx.x >> 6);
        if (row < 3200) {
            const int* r = m + (size_t)row * 257;
            u64 w0 = __ballot(r[lane] != 0);
            u64 w1 = __ballot(r[64 + lane] != 0);
            u64 w2 = __ballot(r[128 + lane] != 0);
            u64 w3 = __ballot(r[192 + lane] != 0);
            u64 w4 = __ballot(lane == 0 && r[256] != 0);
            if (lane == 0) {
                u64* p = mo + (size_t)row * 5;
                p[0] = w0; p[1] = w1; p[2] = w2; p[3] = w3; p[4] = w4;
            }
        }
    }
    int i = cb * 256 + threadIdx.x;
    const int stride = 2048 * 256;
    for (; i < 1916928; i += stride) {
        const float* src; int off;
        if (i < 442368)       { src = s0; off = i; }
        else if (i < 589824)  { src = s1; off = i - 442368; }
        else if (i < 737280)  { src = s2; off = i - 589824; }
        else if (i < 1327104) { src = s3; off = i - 737280; }
        else                  { src = s4; off = i - 1327104; }
        float4 v = ((const float4*)src)[off];
        ushort4 o;
        o.x = f2b(v.x); o.y = f2b(v.y); o.z = f2b(v.z); o.w = f2b(v.w);
        ((ushort4*)dst)[i] = o;
    }
}

// ---------------- LayerNorm standalone (LN2) ----------------
__global__ __launch_bounds__(256) void ln_kernel(
    const float* __restrict__ in, const float* __restrict__ g, const float* __restrict__ be,
    u16* __restrict__ out, int nrows)
{
    int row = blockIdx.x * 4 + (threadIdx.x >> 6);
    if (row < nrows) ln_row(in, g, be, out, row, threadIdx.x & 63);
}

// ---------------- GEMM body: BK=32, 2-buffer, column-group XCD traversal ----------------
// XCD k owns M-tile slice; columns iterated in groups of G (rows inner) so the
// instantaneous L2 working set = A-slice + G B-panels < 4MB.
template<int ACT, int OUTBF, int RES>
__device__ __forceinline__ void gemm_body(
    u16 (*Al)[4096], u16 (*Bl)[4096],
    const u16* __restrict__ A, const u16* __restrict__ B,
    const float* __restrict__ bias, const float* __restrict__ res,
    void* __restrict__ Cp, int M, int N, int K, int G, int gx, int gy, int raw)
{
    const int t = threadIdx.x;
    const int lane = t & 63, w = t >> 6;
    const int wr = w >> 1, wc = w & 1;
    const int fr = lane & 15, fg = lane >> 4;

    const int rows_per = gx >> 3;                 // gx % 8 == 0
    const int xcd = raw & 7, idx = raw >> 3;
    const int bpg = rows_per * G;
    const int grp = idx / bpg, rem = idx - grp * bpg;
    const int nt = grp * G + rem % G;
    const int mt = xcd * rows_per + rem / G;
    const int m0 = mt * 128, n0 = nt * 128;
    if (m0 >= M) return;                          // padded tail block (uniform exit, pre-barrier)

    const int srow = lane >> 2;
    const int scol = (lane & 3) * 8;
    int ar0 = m0 + w * 32 + srow;      int ar1 = ar0 + 16;
    ar0 = ar0 < M ? ar0 : M - 1;       ar1 = ar1 < M ? ar1 : M - 1;
    int br0 = n0 + w * 32 + srow;      int br1 = br0 + 16;
    br0 = br0 < N ? br0 : N - 1;       br1 = br1 < N ? br1 : N - 1;
    const u16* a0p = A + (size_t)ar0 * K + scol;
    const u16* a1p = A + (size_t)ar1 * K + scol;
    const u16* b0p = B + (size_t)br0 * K + scol;
    const u16* b1p = B + (size_t)br1 * K + scol;
    const int lo0 = (w * 2 + 0) * 512, lo1 = (w * 2 + 1) * 512;

    const int nk = K >> 5;
    g2l16(a0p, &Al[0][lo0]);
    g2l16(a1p, &Al[0][lo1]);
    g2l16(b0p, &Bl[0][lo0]);
    g2l16(b1p, &Bl[0][lo1]);
    __syncthreads();

    f32x4 acc[4][4] = {};
#pragma unroll 2
    for (int ki = 0; ki < nk; ++ki) {
        const int cur = ki & 1;
        if (ki + 1 < nk) {               // issue next-tile loads BEFORE compute
            const int k0 = (ki + 1) << 5;
            const int nxt = cur ^ 1;
            g2l16(a0p + k0, &Al[nxt][lo0]);
            g2l16(a1p + k0, &Al[nxt][lo1]);
            g2l16(b0p + k0, &Bl[nxt][lo0]);
            g2l16(b1p + k0, &Bl[nxt][lo1]);
        }
        bf16x8 af[4], bfr[4];
#pragma unroll
        for (int m = 0; m < 4; ++m) af[m] = *(const bf16x8*)&Al[cur][(wr * 64 + m * 16 + fr) * 32 + fg * 8];
#pragma unroll
        for (int n = 0; n < 4; ++n) bfr[n] = *(const bf16x8*)&Bl[cur][(wc * 64 + n * 16 + fr) * 32 + fg * 8];
#pragma unroll
        for (int m = 0; m < 4; ++m)
#pragma unroll
            for (int n = 0; n < 4; ++n)
                acc[m][n] = MFMA16(af[m], bfr[n], acc[m][n]);
        __syncthreads();  // drains this wave's vmcnt(0) (next-tile loads) + barrier
    }
    // Epilogue. C/D layout: col = lane&15, row = (lane>>4)*4 + r  [measured m89/m91]
#pragma unroll
    for (int m = 0; m < 4; ++m) {
#pragma unroll
        for (int n = 0; n < 4; ++n) {
            int col = n0 + wc * 64 + n * 16 + fr;
            float bv = bias[col];
#pragma unroll
            for (int r = 0; r < 4; ++r) {
                int row = m0 + wr * 64 + m * 16 + fg * 4 + r;
                if (row < M) {
                    float v = acc[m][n][r] + bv;
                    if (RES) v += res[(size_t)row * N + col];
                    if (ACT) v = v / (1.f + __expf(-1.702f * v));  // QuickGELU
                    if (OUTBF) ((u16*)Cp)[(size_t)row * N + col] = f2b(v);
                    else       ((float*)Cp)[(size_t)row * N + col] = v;
                }
            }
        }
    }
}

template<int ACT, int OUTBF, int RES>
__global__ __launch_bounds__(256, 4) void gemm_bt(
    const u16* __restrict__ A, const u16* __restrict__ B,
    const float* __restrict__ bias, const float* __restrict__ res,
    void* __restrict__ Cp, int M, int N, int K, int G)
{
    __shared__ u16 Al[2][4096];
    __shared__ u16 Bl[2][4096];
    const int raw = blockIdx.x + gridDim.x * blockIdx.y;
    gemm_body<ACT, OUTBF, RES>(Al, Bl, A, B, bias, res, Cp, M, N, K, G,
                               gridDim.x, gridDim.y, raw);
}

// merged qkv + new_q (both ACT=0, OUTBF=1, RES=0; nq blocks fill qkv's tail)
__global__ __launch_bounds__(256, 4) void gemm_qn(
    const u16* __restrict__ A0, const u16* __restrict__ B0, const float* __restrict__ b0,
    u16* __restrict__ C0,
    const u16* __restrict__ A1, const u16* __restrict__ B1, const float* __restrict__ b1,
    u16* __restrict__ C1)
{
    __shared__ u16 Al[2][4096];
    __shared__ u16 Bl[2][4096];
    const int raw = blockIdx.x;
    if (raw < 1296) {  // qkv: gx=72, gy=18, G=3
        gemm_body<0, 1, 0>(Al, Bl, A0, B0, b0, nullptr, C0, 8224, 2304, 768, 3, 72, 18, raw);
    } else {           // new_q: gx=32, gy=6, G=6
        gemm_body<0, 1, 0>(Al, Bl, A1, B1, b1, nullptr, C1, 3200, 768, 768, 6, 32, 6, raw - 1296);
    }
}

// ---------------- MFMA attention (R14: shfl-PV + tree-max) ----------------
__global__ __launch_bounds__(256, 2) void attn_kernel(
    const u16* __restrict__ qkv,   // [257*32][2304] rows m*32+b; q|k|v at +0/+768/+1536
    const u16* __restrict__ nq,    // [100*32][768]  rows q*32+b
    const u64* __restrict__ mpk,   // [32*100][5] packed mask bits (1 = blocked)
    u16* __restrict__ out)         // [357*32][768]  rows q*32+b
{
    __shared__ u16 Kl[272 * 64];   // K rows, XOR-swizzled: byte ^= (row&7)<<4
    __shared__ u16 Vt[64 * 296];   // Vt[d][m], row stride 592B
    const int raw = blockIdx.x;
    const int bid = (raw & 7) * 48 + (raw >> 3);   // 384 = 8 XCDs x 48 contiguous
    const int b = bid / 12, h = bid % 12;
    const int t = threadIdx.x, lane = t & 63, wv = t >> 6;
    const int fr = lane & 15, fg = lane >> 4;

    for (int i = t; i < 2048; i += 256) {
        int d = i >> 5, c = 257 + (i & 31);
        if (c < 288) Vt[d * 296 + c] = 0;
    }
    {
        const int r8 = t >> 3, c8 = (t & 7) * 8;
        const u16* kb = qkv + 768 + h * 64 + c8;
        const u16* vb = qkv + 1536 + h * 64 + c8;
#pragma unroll 1
        for (int p = 0; p < 9; ++p) {
            int m = r8 + p * 32;
            if (m <= 256) {
                size_t go = (size_t)(m * 32 + b) * 2304;
                bf16x8 kv = *(const bf16x8*)(kb + go);
                int byte = m * 128 + c8 * 2;
                *(bf16x8*)((char*)Kl + (byte ^ ((m & 7) << 4))) = kv;
                bf16x8 vv = *(const bf16x8*)(vb + go);
#pragma unroll
                for (int j = 0; j < 8; ++j)
                    Vt[(c8 + j) * 296 + m] = (u16)vv[j];
            }
        }
    }
    __syncthreads();

    const int swzK = (fr & 7) << 4;
    const char* KlB = (const char*)Kl;
    const char* VtB = (const char*)Vt;
    const int psrc0 = fr + 32 * (fg & 1);          // shfl source lanes for PV redistribution
    const int psrc1 = psrc0 + 16;
    const bool phi = fg >= 2;

    auto fetch = [&](int ti, bf16x8& q0v, bf16x8& q1v, u64* mw, bool& im) {
        int q = ti * 16 + fr;
        int qc = q < 357 ? q : 356;
        im = qc < 100;
        const u16* qp = im ? (nq + (size_t)(qc * 32 + b) * 768 + h * 64)
                           : (qkv + (size_t)((qc - 100) * 32 + b) * 2304 + h * 64);
        q0v = *(const bf16x8*)(qp + fg * 8);
        q1v = *(const bf16x8*)(qp + 32 + fg * 8);
        if (im) {
            const u64* mp = mpk + (size_t)(b * 100 + qc) * 5;
            mw[0] = mp[0]; mw[1] = mp[1]; mw[2] = mp[2]; mw[3] = mp[3]; mw[4] = mp[4];
        } else {
            mw[0] = mw[1] = mw[2] = mw[3] = mw[4] = 0;
        }
    };

    bf16x8 qf0, qf1, qn0, qn1;
    u64 mwc[5], mwn[5];
    bool imc, imn;
    fetch(wv, qf0, qf1, mwc, imc);

#pragma unroll 1
    for (int ti = wv; ti < 23; ti += 4) {
        // ---- QK^T (transposed: acc col = q) ----
        f32x4 sc[17];
#pragma unroll
        for (int kt = 0; kt < 17; ++kt) {
            int rb = (kt * 16 + fr) * 128;
            bf16x8 ka0 = *(const bf16x8*)(KlB + ((rb + fg * 16) ^ swzK));
            bf16x8 ka1 = *(const bf16x8*)(KlB + ((rb + 64 + fg * 16) ^ swzK));
            f32x4 a = {0.f, 0.f, 0.f, 0.f};
            a = MFMA16(ka0, qf0, a);
            a = MFMA16(ka1, qf1, a);
            sc[kt] = a;
        }
        if (ti + 4 < 23) fetch(ti + 4, qn0, qn1, mwn, imn);
        // ---- mask + per-kt max4 (parallel) + tree reduce ----
        float tm[17];
#pragma unroll
        for (int kt = 0; kt < 17; ++kt) {
            u64 mw = (kt >> 2) == 0 ? mwc[0] : (kt >> 2) == 1 ? mwc[1] : (kt >> 2) == 2 ? mwc[2]
                   : (kt >> 2) == 3 ? mwc[3] : mwc[4];
            float s0, s1, s2, s3;
            {
                int key = kt * 16 + fg * 4;
                bool b0 = (key > 256) || (imc && ((mw >> (key & 63)) & 1ull));
                bool b1 = (key + 1 > 256) || (imc && ((mw >> ((key + 1) & 63)) & 1ull));
                bool b2 = (key + 2 > 256) || (imc && ((mw >> ((key + 2) & 63)) & 1ull));
                bool b3 = (key + 3 > 256) || (imc && ((mw >> ((key + 3) & 63)) & 1ull));
                s0 = b0 ? -INFINITY : sc[kt][0];
                s1 = b1 ? -INFINITY : sc[kt][1];
                s2 = b2 ? -INFINITY : sc[kt][2];
                s3 = b3 ? -INFINITY : sc[kt][3];
            }
            sc[kt][0] = s0; sc[kt][1] = s1; sc[kt][2] = s2; sc[kt][3] = s3;
            tm[kt] = fmaxf(fmaxf(s0, s1), fmaxf(s2, s3));
        }
        float m8_0 = fmaxf(tm[0], tm[8]),  m8_1 = fmaxf(tm[1], tm[9]);
        float m8_2 = fmaxf(tm[2], tm[10]), m8_3 = fmaxf(tm[3], tm[11]);
        float m8_4 = fmaxf(tm[4], tm[12]), m8_5 = fmaxf(tm[5], tm[13]);
        float m8_6 = fmaxf(tm[6], tm[14]), m8_7 = fmaxf(tm[7], tm[15]);
        float m4_0 = fmaxf(m8_0, m8_4), m4_1 = fmaxf(m8_1, m8_5);
        float m4_2 = fmaxf(m8_2, m8_6), m4_3 = fmaxf(m8_3, m8_7);
        float mx = fmaxf(fmaxf(fmaxf(m4_0, m4_1), fmaxf(m4_2, m4_3)), tm[16]);
        mx = fmaxf(mx, __shfl_xor(mx, 16));
        mx = fmaxf(mx, __shfl_xor(mx, 32));
        // ---- exp (scale folded), sum, pack to bf16 pairs ----
        float l = 0.f;
        unsigned pk[17][2];
#pragma unroll
        for (int kt = 0; kt < 17; ++kt) {
            float p0 = __expf((sc[kt][0] - mx) * 0.125f);
            float p1 = __expf((sc[kt][1] - mx) * 0.125f);
            float p2 = __expf((sc[kt][2] - mx) * 0.125f);
            float p3 = __expf((sc[kt][3] - mx) * 0.125f);
            l += (p0 + p1) + (p2 + p3);
            pk[kt][0] = pack2(p0, p1);
            pk[kt][1] = pack2(p2, p3);
        }
        l += __shfl_xor(l, 16);
        l += __shfl_xor(l, 32);
        // ---- PV: O^T = V^T * P^T, P redistributed via shfl (no LDS round-trip) ----
        f32x4 oc[4] = {};
#pragma unroll
        for (int c = 0; c < 9; ++c) {
            unsigned p00 = pk[2 * c][0], p01 = pk[2 * c][1];
            unsigned p10 = (c < 8) ? pk[2 * c + 1][0] : 0u;
            unsigned p11 = (c < 8) ? pk[2 * c + 1][1] : 0u;
            unsigned a00 = __shfl(p00, psrc0), a01 = __shfl(p01, psrc0);
            unsigned a10 = __shfl(p10, psrc0), a11 = __shfl(p11, psrc0);
            unsigned b00 = __shfl(p00, psrc1), b01 = __shfl(p01, psrc1);
            unsigned b10 = __shfl(p10, psrc1), b11 = __shfl(p11, psrc1);
            uint4 pw;
            pw.x = phi ? a10 : a00;  pw.y = phi ? a11 : a01;
            pw.z = phi ? b10 : b00;  pw.w = phi ? b11 : b01;
            bf16x8 pf = __builtin_bit_cast(bf16x8, pw);
#pragma unroll
            for (int dt = 0; dt < 4; ++dt) {
                bf16x8 vf = *(const bf16x8*)(VtB + (dt * 16 + fr) * 592 + c * 64 + fg * 16);
                oc[dt] = MFMA16(vf, pf, oc[dt]);
            }
        }
        // ---- write O (lane q = fr, d = dt*16 + fg*4 + r) ----
        int q = ti * 16 + fr;
        if (q < 357) {
            float rl = 1.f / l;
            u16* op = out + (size_t)(q * 32 + b) * 768 + h * 64 + fg * 4;
#pragma unroll
            for (int dt = 0; dt < 4; ++dt) {
                ushort4 ov;
                ov.x = f2b(oc[dt][0] * rl); ov.y = f2b(oc[dt][1] * rl);
                ov.z = f2b(oc[dt][2] * rl); ov.w = f2b(oc[dt][3] * rl);
                *(ushort4*)(op + dt * 16) = ov;
            }
        }
        if (ti + 4 < 23) {
            qf0 = qn0; qf1 = qn1; imc = imn;
            mwc[0] = mwn[0]; mwc[1] = mwn[1]; mwc[2] = mwn[2]; mwc[3] = mwn[3]; mwc[4] = mwn[4];
        }
    }
}

// ---------------- launch ----------------
extern "C" void kernel_launch(void* const* d_in, const int* in_sizes, int n_in,
                              void* d_out, int out_size, void* d_ws, size_t ws_size,
                              hipStream_t stream)
{
    const float* y   = (const float*)d_in[0];
    const int*   msk = (const int*)  d_in[1];
    const float* ipw = (const float*)d_in[2];
    const float* ipb = (const float*)d_in[3];
    const float* nqw = (const float*)d_in[4];
    const float* nqb = (const float*)d_in[5];
    const float* ow  = (const float*)d_in[6];
    const float* ob  = (const float*)d_in[7];
    const float* l1g = (const float*)d_in[8];
    const float* l1b = (const float*)d_in[9];
    const float* l2g = (const float*)d_in[10];
    const float* l2b = (const float*)d_in[11];
    const float* fcw = (const float*)d_in[12];
    const float* fcb = (const float*)d_in[13];
    const float* pjw = (const float*)d_in[14];
    const float* pjb = (const float*)d_in[15];

    char* ws = (char*)d_ws;
    u16* x_b   = (u16*)(ws + 0);          // 11424 x 768
    u16* qkv_b = (u16*)(ws + 17547264);   //  8224 x 2304
    u16* nq_b  = (u16*)(ws + 55443456);   //  3200 x 768
    u16* ao_b  = (u16*)(ws + 60358656);   // 11424 x 768
    u16* h1_b  = (u16*)(ws + 0);          // 11424 x 3072 (phase 2, overlaps phase-1 region)
    u16* h_b   = (u16*)(ws + 77905920);   // 11424 x 768 (phase 2)
    u64* mpk_b = (u64*)(ws + 77905920);   // 3200 x 5 u64 (phase 1 only)
    u16* w_ip  = (u16*)(ws + 95453184);   // weights contiguous: ip|nq|out|fc|pj
    float* out = (float*)d_out;

    u16* w_nq  = w_ip + 1769472;
    u16* w_out = w_nq + 589824;
    u16* w_fc  = w_out + 589824;
    u16* w_pj  = w_fc + 2359296;

    // LN1 + mask-pack + weight-cvt fused
    prep_ln<<<4904, 256, 0, stream>>>(y, l1g, l1b, x_b, msk, mpk_b, ipw, nqw, ow, fcw, pjw, w_ip);
    // qkv + new_q fused (1296 + 192 blocks)
    gemm_qn<<<1488, 256, 0, stream>>>(x_b + (size_t)3200 * 768, w_ip, ipb, qkv_b,
                                      x_b, w_nq, nqb, nq_b);
    // attention
    attn_kernel<<<384, 256, 0, stream>>>(qkv_b, nq_b, mpk_b, ao_b);
    // y2 = y + attn_out @ out_w.T + out_b   (G=gy)
    gemm_bt<0, 0, 1><<<dim3(96, 6), 256, 0, stream>>>(ao_b, w_out, ob, y, out, 11424, 768, 768, 6);
    // h = LN2(y2) -> bf16
    ln_kernel<<<2856, 256, 0, stream>>>(out, l2g, l2b, h_b, 11424);
    // h1 = quickgelu(h @ fc_w.T + fc_b)   (G=4)
    gemm_bt<1, 1, 0><<<dim3(96, 24), 256, 0, stream>>>(h_b, w_fc, fcb, nullptr, h1_b, 11424, 3072, 768, 4);
    // out = y2 + h1 @ proj_w.T + proj_b   (G=3)
    gemm_bt<0, 0, 1><<<dim3(96, 6), 256, 0, stream>>>(h1_b, w_pj, pjb, out, out, 11424, 768, 3072, 3);
}